// Round 5
// baseline (345.532 us; speedup 1.0000x reference)
//
#include <hip/hip_runtime.h>
#include <math.h>

namespace {
constexpr int D     = 192;
constexpr int HW    = 256 * 512;   // 131072 = 2^17
constexpr int TOTAL = 2 * HW;      // 262144 pixels

// Correctly-rounded s/5 in 3 ops (Markstein): bit-exact vs IEEE s/5.0f for
// all normal s >= 0 (our s in [0,5)).
__device__ __forceinline__ float div5(float s) {
    const float c = 0.2f;
    float q = s * c;
    float r = __builtin_fmaf(-5.0f, q, s);
    return __builtin_fmaf(r, c, q);
}

__device__ __forceinline__ bool in_range(int d, int lo, unsigned width) {
    return (unsigned)(d - lo) <= width;
}

// Per-segment augmented modal state machine (mergeable across a lane pair).
// Sentinels: last_fall / index_l = -1 => "no fall in this segment" (B only);
// first_rise = -1 => "no rise in this segment".
struct SegMachine {
    float bprev, maxv;
    int   index, last_fall, index_l, index_r, first_rise;
    bool  r_found;

    __device__ __forceinline__ void init(float bp, bool isB) {
        bprev = bp; maxv = -INFINITY; index = 0;
        last_fall = isB ? -1 : 0;      // A keeps original init 0 ("no fall" -> 0)
        index_l   = isB ? -1 : 0;
        index_r = D - 1; first_rise = -1; r_found = false;
    }

    __device__ __forceinline__ void step(int d, float b) {
        float diff = b - bprev;
        bool fall  = diff < 0.0f;
        last_fall  = fall ? d : last_fall;
        bool am    = b > maxv;                         // first-occurrence argmax
        maxv       = fmaxf(b, maxv);
        index      = am ? d : index;
        index_l    = am ? last_fall : index_l;
        bool rise  = diff > 0.0f;
        first_rise = (rise && (first_rise < 0)) ? d : first_rise;
        bool ra    = rise & (!r_found) & (!am);        // first rise AFTER argmax
        index_r    = am ? (D - 1) : (ra ? (d - 1) : index_r);
        r_found    = am ? false : (r_found | ra);
        bprev      = b;
    }
};

// Exchange segment summaries across the lane pair (xor 32) and compute the
// merged full-column mask bounds. Exact vs the monolithic machine:
//  - argmax: A wins ties (first occurrence).
//  - index_l: if argmax in B and B has no fall <= its argmax, inherit A's
//    last fall anywhere (falls in A are all <= any B position).
//  - index_r: if argmax in A and A found no rise after it, the first rise
//    anywhere in B continues the search; default D-1 (append-ones).
__device__ __forceinline__ void merge_bounds(const SegMachine& me, bool isB,
                                             int& lo, unsigned& wd) {
    float o_maxv  = __shfl_xor(me.maxv, 32);
    int o_index   = __shfl_xor(me.index, 32);
    int o_index_l = __shfl_xor(me.index_l, 32);
    int o_index_r = __shfl_xor(me.index_r, 32);
    int o_lf      = __shfl_xor(me.last_fall, 32);
    int o_fr      = __shfl_xor(me.first_rise, 32);
    int o_rf      = __shfl_xor((int)me.r_found, 32);

    float Amax = isB ? o_maxv : me.maxv;
    int  Aidx  = isB ? o_index   : me.index;
    int  Ail   = isB ? o_index_l : me.index_l;
    int  Air   = isB ? o_index_r : me.index_r;
    int  Alf   = isB ? o_lf      : me.last_fall;
    bool Arf   = isB ? (o_rf != 0) : me.r_found;
    float Bmax = isB ? me.maxv : o_maxv;
    int  Bidx  = isB ? me.index   : o_index;
    int  Bil   = isB ? me.index_l : o_index_l;
    int  Bir   = isB ? me.index_r : o_index_r;
    int  Bfr   = isB ? me.first_rise : o_fr;

    bool inA    = Amax >= Bmax;
    int index   = inA ? Aidx : Bidx;
    int index_l = inA ? Ail : (Bil >= 0 ? Bil : Alf);
    int index_r = inA ? (Arf ? Air : (Bfr >= 0 ? Bfr - 1 : D - 1)) : Bir;

    int r = min(index_r - index, index - index_l);
    int t = 2 * index - index_r - index_l;
    bool valid = (t > -3) && (t < 3);
    lo = valid ? index_l : (index - r);
    int hi = valid ? index_r : (index + r);
    wd = (unsigned)(hi - lo);
}

// Stream 96 blur steps from depth d0 with an 8-deep double-buffered prefetch.
// Window invariant at step d: w0=x[d-2] w1=x[d-1] w2=x[d] w3=x[d+1], L=x[d+2].
// F(d, b, xv) gets the blur value b[d] (bit-exact ref order) and xv=x[d].
template<typename F>
__device__ __forceinline__ void stream96(const float* __restrict__ col, int d0,
                                         float w0, float w1, float w2, float w3,
                                         F&& f) {
    float cur[8], nxt[8];
    #pragma unroll
    for (int j = 0; j < 8; ++j) cur[j] = col[(size_t)(d0 + 2 + j) * HW];
    int d = d0;
    for (int k = 0; k < 11; ++k) {
        int base = d0 + 10 + 8 * k;
        if (k < 10) {
            #pragma unroll
            for (int j = 0; j < 8; ++j) nxt[j] = col[(size_t)(base + j) * HW];
        } else {
            // last prefetch: for B (d0=96) indices 186..193 -> guard >= D
            #pragma unroll
            for (int j = 0; j < 8; ++j) {
                int idx = base + j;
                float v = col[(size_t)min(idx, D - 1) * HW];
                nxt[j] = (idx < D) ? v : 0.0f;
            }
        }
        #pragma unroll
        for (int j = 0; j < 8; ++j) {
            float s = w0 + w1; s += w2; s += w3; s += cur[j];  // exact ref order
            f(d, div5(s), w2);
            w0 = w1; w1 = w2; w2 = w3; w3 = cur[j]; ++d;
        }
        #pragma unroll
        for (int j = 0; j < 8; ++j) cur[j] = nxt[j];
    }
    #pragma unroll
    for (int j = 0; j < 8; ++j) {
        float s = w0 + w1; s += w2; s += w3; s += cur[j];
        f(d, div5(s), w2);
        w0 = w1; w1 = w2; w2 = w3; w3 = cur[j]; ++d;
    }
}
} // namespace

extern "C" __global__ void __launch_bounds__(256, 8)
dme_kernel(const float* __restrict__ x, float* __restrict__ out)
{
    // Lane pair (i, i+32) shares one pixel column: A scans d=0..95, B 96..191.
    const int  lane = threadIdx.x & 63;
    const int  wv   = threadIdx.x >> 6;
    const bool isB  = lane >= 32;
    const int  pix  = blockIdx.x * 128 + wv * 32 + (lane & 31);
    const int  n    = pix >> 17;
    const int  hw   = pix & (HW - 1);
    const float* __restrict__ col = x + (size_t)n * (size_t)(D * HW) + hw;

    const int d0 = isB ? 96 : 0;

    // Setup: A loads x[0..4] (uses x[0],x[1]); B loads x[93..97] and computes
    // b[95] (its incoming bprev) independently of A's scan.
    float t0, t1, t2, t3, t4;
    {
        int b0 = isB ? 93 : 0;
        t0 = col[(size_t)(b0 + 0) * HW];
        t1 = col[(size_t)(b0 + 1) * HW];
        t2 = col[(size_t)(b0 + 2) * HW];
        t3 = col[(size_t)(b0 + 3) * HW];
        t4 = col[(size_t)(b0 + 4) * HW];
    }
    float s95 = t0 + t1; s95 += t2; s95 += t3; s95 += t4;   // exact ref order
    s95 = div5(s95);                                        // = b[95] (B lanes)
    const float w0i = isB ? t1 : 0.f;
    const float w1i = isB ? t2 : 0.f;
    const float w2i = isB ? t3 : t0;
    const float w3i = isB ? t4 : t1;

    // ---------------- pass 1: modal mask of blur(x) ----------------
    SegMachine m1; m1.init(isB ? s95 : 1.0f, isB);
    stream96(col, d0, w0i, w1i, w2i, w3i,
             [&](int d, float b, float) { m1.step(d, b); });
    int lo1; unsigned wd1;
    merge_bounds(m1, isB, lo1, wd1);

    // -------- pass 2: modal mask of blur(x) * ~mask1 --------
    float bp2 = isB ? (in_range(95, lo1, wd1) ? 0.0f : s95) : 1.0f;
    SegMachine m2; m2.init(bp2, isB);
    stream96(col, d0, w0i, w1i, w2i, w3i,
             [&](int d, float b, float) {
                 m2.step(d, in_range(d, lo1, wd1) ? 0.0f : b);
             });
    int lo2; unsigned wd2;
    merge_bounds(m2, isB, lo2, wd2);

    // -------- sums pass: full 192-step sequential fold, lane-specialized --------
    // A-lane folds y = x*mask1; B-lane folds z = x*mask2nd*~mask1 — each in the
    // exact d=0..191 order of the R4 kernel (bitwise-identical accumulators).
    float sum = 0.f, wsum = 0.f, fd = 0.f;
    const int loS = isB ? lo2 : lo1;
    const unsigned wdS = isB ? wd2 : wd1;
    {
        float cur[8], nxt[8];
        #pragma unroll
        for (int j = 0; j < 8; ++j) cur[j] = col[(size_t)j * HW];
        int d = 0;
        for (int k = 0; k < 23; ++k) {
            #pragma unroll
            for (int j = 0; j < 8; ++j) nxt[j] = col[(size_t)(8 * k + 8 + j) * HW];
            #pragma unroll
            for (int j = 0; j < 8; ++j) {
                bool inS = in_range(d, loS, wdS);
                bool use = isB ? (inS & !in_range(d, lo1, wd1)) : inS;
                float term = use ? cur[j] : 0.f;
                sum += term;
                wsum = __builtin_fmaf(fd, term, wsum);
                ++d; fd += 1.0f;
            }
            #pragma unroll
            for (int j = 0; j < 8; ++j) cur[j] = nxt[j];
        }
        #pragma unroll
        for (int j = 0; j < 8; ++j) {
            bool inS = in_range(d, loS, wdS);
            bool use = isB ? (inS & !in_range(d, lo1, wd1)) : inS;
            float term = use ? cur[j] : 0.f;
            sum += term;
            wsum = __builtin_fmaf(fd, term, wsum);
            ++d; fd += 1.0f;
        }
    }

    // Pair up: A has (sum_y, wsum_y), B has (sum_z, wsum_z).
    float o_sum  = __shfl_xor(sum, 32);
    float o_wsum = __shfl_xor(wsum, 32);
    if (!isB) {
        bool  v = (sum >= o_sum);                 // sum_y >= sum_z
        float Ssel = v ? sum  : o_sum;
        float Wsel = v ? wsum : o_wsum;
        out[pix] = Wsel / Ssel;
    }
}

extern "C" void kernel_launch(void* const* d_in, const int* in_sizes, int n_in,
                              void* d_out, int out_size, void* d_ws, size_t ws_size,
                              hipStream_t stream)
{
    const float* x   = (const float*)d_in[0];
    float*       out = (float*)d_out;
    dim3 block(256), grid(TOTAL / 128);     // 2048 blocks; 2 lanes per pixel
    hipLaunchKernelGGL(dme_kernel, grid, block, 0, stream, x, out);
}

// Round 6
// 324.957 us; speedup vs baseline: 1.0633x; 1.0633x over previous
//
#include <hip/hip_runtime.h>
#include <math.h>

namespace {
constexpr int D     = 192;
constexpr int HW    = 256 * 512;   // 131072 = 2^17
constexpr int TOTAL = 2 * HW;      // 262144 pixels

// Correctly-rounded s/5 in 3 ops (Markstein): bit-exact vs IEEE s/5.0f for
// all normal s >= 0 (our s in [0,5)).
__device__ __forceinline__ float div5(float s) {
    const float c = 0.2f;
    float q = s * c;
    float r = __builtin_fmaf(-5.0f, q, s);
    return __builtin_fmaf(r, c, q);
}

__device__ __forceinline__ bool in_range(int d, int lo, unsigned width) {
    return (unsigned)(d - lo) <= width;
}

// Streaming modal-mask state machine, bit-exact vs the numpy reference.
struct Machine {
    float bprev, maxv;
    int   index, last_fall, index_l, index_r;
    bool  r_found;

    __device__ __forceinline__ void init() {
        bprev = 1.0f;          // "ones" prepend: diff at d=0 is b0 - 1 < 0 -> fall
        maxv  = -INFINITY;
        index = 0; last_fall = 0; index_l = 0;
        index_r = D - 1;       // default: rise at virtual position D (append ones)
        r_found = false;
    }

    __device__ __forceinline__ void step(int d, float b) {
        float diff = b - bprev;
        bool fall  = diff < 0.0f;
        last_fall  = fall ? d : last_fall;               // strict fall
        bool am    = b > maxv;                           // first-occurrence argmax
        maxv       = am ? b : maxv;
        index      = am ? d : index;
        index_l    = am ? last_fall : index_l;           // last fall <= new argmax
        bool rise  = (diff > 0.0f) & (!r_found) & (!am); // first strict rise AFTER argmax
        index_r    = am ? (D - 1) : (rise ? (d - 1) : index_r);
        r_found    = am ? false : (r_found | rise);
        bprev      = b;
    }

    __device__ __forceinline__ void finish(int& lo, unsigned& wd) const {
        int r = min(index_r - index, index - index_l);
        int t = 2 * index - index_r - index_l;
        bool valid = (t > -3) && (t < 3);
        lo = valid ? index_l : (index - r);
        int hi = valid ? index_r : (index + r);
        wd = (unsigned)(hi - lo);
    }
};

// OFS=2: chunk c supplies x[8c+2+j] (the d+2 lookahead for the blur window).
// OFS=0: chunk c supplies x[8c+j] (plain streaming for the sums pass).
template<int OFS>
__device__ __forceinline__ void loadc(const float* __restrict__ col, int c,
                                      float (&buf)[8]) {
    #pragma unroll
    for (int j = 0; j < 8; ++j)
        buf[j] = col[(size_t)(8 * c + OFS + j) * HW];
}
template<int OFS>
__device__ __forceinline__ void loadc_guard(const float* __restrict__ col, int c,
                                            float (&buf)[8]) {
    #pragma unroll
    for (int j = 0; j < 8; ++j) {
        int idx = 8 * c + OFS + j;
        buf[j] = (idx < D) ? col[(size_t)idx * HW] : 0.0f;
    }
}

// 24 chunks of 8 depths, 3-buffer rotating software pipeline with a constant
// TWO-chunk load->use distance (~850 cyc of VALU between issue and wait),
// sized to cover the ~900 cyc HBM latency that capped VALUBusy at ~55%.
// Positional rotation (3 chunks per loop iteration) -> no buffer-copy movs.
template<int OFS, typename F>
__device__ __forceinline__ void stream24(const float* __restrict__ col, F&& f) {
    float A[8], B[8], C[8];
    loadc<OFS>(col, 0, A);
    loadc<OFS>(col, 1, B);
    loadc<OFS>(col, 2, C);
    int d = 0;
    auto comp = [&](float (&buf)[8]) {
        #pragma unroll
        for (int j = 0; j < 8; ++j) { f(d, buf[j]); ++d; }
    };
    for (int g = 0; g < 6; ++g) {          // chunks 3g..3g+2, issue 3g+3..3g+5
        comp(A); loadc<OFS>(col, 3 * g + 3, A);
        comp(B); loadc<OFS>(col, 3 * g + 4, B);
        comp(C); loadc<OFS>(col, 3 * g + 5, C);
    }
    // g == 6: computes 18..20, issues 21,22 plain; 23 needs the OOB guard
    // only in lookahead mode (indices 186..193; 192,193 -> 0).
    comp(A); loadc<OFS>(col, 21, A);
    comp(B); loadc<OFS>(col, 22, B);
    comp(C);
    if (OFS == 2) loadc_guard<OFS>(col, 23, C);
    else          loadc<OFS>(col, 23, C);
    // g == 7: drain
    comp(A); comp(B); comp(C);
}
} // namespace

extern "C" __global__ void __launch_bounds__(256, 4)
dme_kernel(const float* __restrict__ x, float* __restrict__ out)
{
    // n is block-uniform: 512 blocks per image -> base pointer lives in SGPRs.
    const int n  = blockIdx.x >> 9;
    const int hw = ((blockIdx.x & 511) << 8) | threadIdx.x;
    const float* __restrict__ col = x + (size_t)n * (size_t)(D * HW) + hw;

    const float x0 = col[0];
    const float x1 = col[HW];

    // ================= pass 1: modal mask of blur(x) =================
    Machine m1; m1.init();
    {
        float w0 = 0.f, w1 = 0.f, w2 = x0, w3 = x1;
        stream24<2>(col, [&](int d, float xv) {
            // exact left-to-right window sum, matching reference add order
            float s = w0 + w1; s += w2; s += w3; s += xv;
            m1.step(d, div5(s));
            w0 = w1; w1 = w2; w2 = w3; w3 = xv;
        });
    }
    int lo1; unsigned wd1; m1.finish(lo1, wd1);

    // ====== pass 2: modal mask of blur(x)*~mask1, plus y-sums ======
    Machine m2; m2.init();
    float sum_y = 0.f, wsum_y = 0.f;
    {
        float w0 = 0.f, w1 = 0.f, w2 = x0, w3 = x1;
        float fd = 0.0f;
        stream24<2>(col, [&](int d, float xv) {
            float s = w0 + w1; s += w2; s += w3; s += xv;
            float b = div5(s);
            bool in1 = in_range(d, lo1, wd1);
            m2.step(d, in1 ? 0.0f : b);          // x_blur2 = x_blur * ~mask1
            sum_y += in1 ? w2 : 0.f;             // y = x*mask1; x[d] == w2
            float t = in1 ? fd : 0.f;
            wsum_y = __builtin_fmaf(t, w2, wsum_y);
            w0 = w1; w1 = w2; w2 = w3; w3 = xv; fd += 1.0f;
        });
    }
    int lo2; unsigned wd2; m2.finish(lo2, wd2);

    // ========= pass 3: z-sums (z = x * ~mask1 * mask2nd) =========
    float sum_z = 0.f, wsum_z = 0.f;
    {
        float fd = 0.0f;
        stream24<0>(col, [&](int d, float xv) {
            bool z = in_range(d, lo2, wd2) & !in_range(d, lo1, wd1);
            sum_z += z ? xv : 0.f;
            float t = z ? fd : 0.f;
            wsum_z = __builtin_fmaf(t, xv, wsum_z);
            fd += 1.0f;
        });
    }

    bool  v = (sum_y >= sum_z);
    float S = v ? sum_y  : sum_z;
    float W = v ? wsum_y : wsum_z;
    out[hw + n * HW] = W / S;    // == sum(xm*d)/sum(xm)
}

extern "C" void kernel_launch(void* const* d_in, const int* in_sizes, int n_in,
                              void* d_out, int out_size, void* d_ws, size_t ws_size,
                              hipStream_t stream)
{
    const float* x   = (const float*)d_in[0];
    float*       out = (float*)d_out;
    dim3 block(256), grid(TOTAL / 256);          // 1024 blocks, 16 waves/CU
    hipLaunchKernelGGL(dme_kernel, grid, block, 0, stream, x, out);
}